// Round 2
// baseline (3568.599 us; speedup 1.0000x reference)
//
#include <hip/hip_runtime.h>
#include <math.h>

#define BB 512   // batch
#define TT 2048  // timesteps
#define DD 64    // input dim
#define HH 66    // hidden
#define GG 264   // 4*HH gates
#define GP 272   // padded gates (17 mfma n-tiles of 16)
#define NTILE 17
#define XSS 68   // xstage row stride (floats)
#define NSUB 128 // 128 subchunks x 16 steps = 2048

typedef __attribute__((ext_vector_type(8))) __bf16 bf8_t;
typedef __attribute__((ext_vector_type(8))) unsigned short us8_t;
typedef __attribute__((ext_vector_type(4))) float f4_t;

__device__ __forceinline__ float fast_sigmoid(float x) {
  float e = __expf(-x);
  return __fdividef(1.0f, 1.0f + e);
}
__device__ __forceinline__ float fast_tanh(float x) {
  float e = __expf(2.0f * x);
  return 1.0f - __fdividef(2.0f, e + 1.0f);
}
__device__ __forceinline__ unsigned short f2bf(float f) {
  unsigned u = __builtin_bit_cast(unsigned, f);
  unsigned r = (u + 0x7fffu + ((u >> 16) & 1u)) >> 16;
  return (unsigned short)r;
}
__device__ __forceinline__ float bf2f(unsigned short h) {
  unsigned u = ((unsigned)h) << 16;
  return __builtin_bit_cast(float, u);
}
static __device__ __forceinline__ bf8_t as_bf8(us8_t u) {
  union { us8_t u; bf8_t b; } v; v.u = u; return v.b;
}
__device__ __forceinline__ void pack_hilo(float4 p0, float4 p1, us8_t& hi, us8_t& lo) {
  float v[8] = {p0.x, p0.y, p0.z, p0.w, p1.x, p1.y, p1.z, p1.w};
#pragma unroll
  for (int i = 0; i < 8; ++i) {
    unsigned short h = f2bf(v[i]);
    hi[i] = h;
    lo[i] = f2bf(v[i] - bf2f(h));
  }
}

// 66 named scalar registers for the W_hh row: SSA values, cannot be demoted
// to scratch (R1/R2: whh[66] array failed SROA -> VGPR_Count=84 -> scratch
// reloads every step were the dominant stall). Prefix wr to avoid colliding
// with local identifiers (R3 compile failure: w4).
#define RL64(X) \
  X(0) X(1) X(2) X(3) X(4) X(5) X(6) X(7) X(8) X(9) \
  X(10) X(11) X(12) X(13) X(14) X(15) X(16) X(17) X(18) X(19) \
  X(20) X(21) X(22) X(23) X(24) X(25) X(26) X(27) X(28) X(29) \
  X(30) X(31) X(32) X(33) X(34) X(35) X(36) X(37) X(38) X(39) \
  X(40) X(41) X(42) X(43) X(44) X(45) X(46) X(47) X(48) X(49) \
  X(50) X(51) X(52) X(53) X(54) X(55) X(56) X(57) X(58) X(59) \
  X(60) X(61) X(62) X(63)

#define DECLW(i) float wr##i;
#define LOADW(i) wr##i = p[(i)];
// R5: h lives in registers wave-locally. Lane i of EVERY wave holds h[i]
// (redundant cell update), so broadcast is readlane(ha, i) directly.
// acc[i&3] rotates deps at distance 4.
#define FMAW(i)                                                               \
  {                                                                           \
    float hj = __builtin_bit_cast(                                            \
        float, __builtin_amdgcn_readlane(__builtin_bit_cast(int, ha), (i)));  \
    acc[(i) & 3] = fmaf(hj, wr##i, acc[(i) & 3]);                             \
  }

// Kernel 0: W_ih fp32 -> bf16 hi/lo, padded to 272 rows of 64.
__global__ void conv_w(const float* __restrict__ W_ih,
                       unsigned short* __restrict__ hi,
                       unsigned short* __restrict__ lo) {
  int i = blockIdx.x * 256 + threadIdx.x;
  if (i >= GP * DD) return;
  int n = i >> 6;
  float w = (n < GG) ? W_ih[i] : 0.0f;
  unsigned short h = f2bf(w);
  hi[i] = h;
  lo[i] = f2bf(w - bf2f(h));
}

// 2 sequences per block (wave-aligned halves: tid 0..319 -> seq A,
// 320..639 -> seq B). Grid = 256 = exactly 1 block/CU (R4: occupancy 15%
// showed the 512x320 grid ran as 2 sequential rounds).
// R5: ONE barrier per step. Every thread redundantly computes the cell
// update for j=lane (+ j=64+(lane&1)), so each wave holds the full h
// vector in registers -> no h LDS round-trip, no second barrier. sact is
// double-buffered on step parity so the s+1 gate write can't WAR the
// step-s cell-update reads (the single barrier separates them).
__global__ __launch_bounds__(640, 2) void lstm_fused(
    const float* __restrict__ x,      // [B,T,D]
    const float* __restrict__ W_hh,   // [264,66]
    const float* __restrict__ b_ih,   // [264]
    const float* __restrict__ b_hh,   // [264]
    const unsigned short* __restrict__ WbHi,  // [272,64] bf16
    const unsigned short* __restrict__ WbLo,  // [272,64] bf16
    float* __restrict__ hT)           // [66,512]
{
  __shared__ __align__(16) float tr[2][16 * GP];          // [half][tc][g]
  __shared__ __align__(16) float xstage[2][2][16 * XSS];  // [half][buf] x rows
  __shared__ __align__(16) float sact[2][2][GG];          // [half][parity][g]

  const int half = (int)(threadIdx.x >= 320);
  const int tid = threadIdx.x - 320 * half;  // 0..319 within half
  const int b = blockIdx.x * 2 + half;
  const int l = tid & 63;   // == threadIdx.x & 63 (half boundary is wave-aligned)
  const int w = tid >> 6;
  const bool gate = (tid < GG);
  const bool mm = (tid < 256);
  const bool isW4 = (w == 4);
  const int mlane = l & 15;
  const int quad = l >> 4;
  const int jb = 64 + (l & 1);  // second cell index per lane (h64/h65)

  // W_hh row in 66 named scalars (clamped row for non-gate threads).
  RL64(DECLW) float wr64, wr65;
  {
    const int row = gate ? tid : (GG - 1);
    const float* p = W_hh + row * HH;
    RL64(LOADW) wr64 = p[64]; wr65 = p[65];
  }
  const bool istanh = (tid >= 2 * HH && tid < 3 * HH);

  float biasCol[5];
#pragma unroll
  for (int ti = 0; ti < 5; ++ti) {
    int tau = w + 4 * ti;
    int g = tau * 16 + mlane;
    biasCol[ti] = (mm && tau < NTILE && g < GG) ? (b_ih[g] + b_hh[g]) : 0.0f;
  }

  if (isW4) {
    const int r = l >> 2, cq = l & 3;
    const float* src = x + ((size_t)b * TT + r) * DD + cq * 16;
    float4 v0 = *(const float4*)(src + 0);
    float4 v1 = *(const float4*)(src + 4);
    float4 v2 = *(const float4*)(src + 8);
    float4 v3 = *(const float4*)(src + 12);
    float* dst = &xstage[half][0][r * XSS + cq * 16];
    *(float4*)(dst + 0) = v0; *(float4*)(dst + 4) = v1;
    *(float4*)(dst + 8) = v2; *(float4*)(dst + 12) = v3;
  }
  // Redundant per-wave LSTM state: lane i holds (c,h) for j=i, plus
  // (cb,hb) for j=64+(i&1). All 64 lanes of all waves stay valid so
  // readlane always reads live data.
  float ca = 0.0f, ha = 0.0f, cb = 0.0f, hb = 0.0f;
  __syncthreads();

  for (int sc = 0; sc < NSUB; ++sc) {
    // ---- x-projection (bf16 hi/lo MFMA) for the next 16 steps ----
    if (mm) {
      const float* xs = &xstage[half][sc & 1][0];
      float4 a00 = *(const float4*)&xs[mlane * XSS + quad * 8];
      float4 a01 = *(const float4*)&xs[mlane * XSS + quad * 8 + 4];
      float4 a10 = *(const float4*)&xs[mlane * XSS + 32 + quad * 8];
      float4 a11 = *(const float4*)&xs[mlane * XSS + 32 + quad * 8 + 4];
      us8_t ah0, al0, ah1, al1;
      pack_hilo(a00, a01, ah0, al0);
      pack_hilo(a10, a11, ah1, al1);
#pragma unroll
      for (int ti = 0; ti < 5; ++ti) {
        int tau = w + 4 * ti;
        if (tau < NTILE) {
          int n = tau * 16 + mlane;
          const us8_t* bh = (const us8_t*)(WbHi + n * DD + quad * 8);
          const us8_t* bl = (const us8_t*)(WbLo + n * DD + quad * 8);
          us8_t bh0 = bh[0], bh1 = bh[4];
          us8_t bl0 = bl[0], bl1 = bl[4];
          f4_t acc = {biasCol[ti], biasCol[ti], biasCol[ti], biasCol[ti]};
          acc = __builtin_amdgcn_mfma_f32_16x16x32_bf16(as_bf8(ah0), as_bf8(bh0), acc, 0, 0, 0);
          acc = __builtin_amdgcn_mfma_f32_16x16x32_bf16(as_bf8(ah1), as_bf8(bh1), acc, 0, 0, 0);
          acc = __builtin_amdgcn_mfma_f32_16x16x32_bf16(as_bf8(al0), as_bf8(bh0), acc, 0, 0, 0);
          acc = __builtin_amdgcn_mfma_f32_16x16x32_bf16(as_bf8(al1), as_bf8(bh1), acc, 0, 0, 0);
          acc = __builtin_amdgcn_mfma_f32_16x16x32_bf16(as_bf8(ah0), as_bf8(bl0), acc, 0, 0, 0);
          acc = __builtin_amdgcn_mfma_f32_16x16x32_bf16(as_bf8(ah1), as_bf8(bl1), acc, 0, 0, 0);
          int g = tau * 16 + mlane;
#pragma unroll
          for (int r = 0; r < 4; ++r) tr[half][(quad * 4 + r) * GP + g] = acc[r];
        }
      }
    }
    __syncthreads();  // tr ready

    const int scn = sc + 1;
    float4 pf0, pf1, pf2, pf3;
    if (isW4 && scn < NSUB) {
      const int r = l >> 2, cq = l & 3;
      const float* src = x + ((size_t)b * TT + scn * 16 + r) * DD + cq * 16;
      pf0 = *(const float4*)(src + 0);
      pf1 = *(const float4*)(src + 4);
      pf2 = *(const float4*)(src + 8);
      pf3 = *(const float4*)(src + 12);
    }

    for (int s = 0; s < 16; ++s) {
      if (gate) {
        float acc[4];
        acc[0] = tr[half][s * GP + tid];  // x_proj + bias
        acc[1] = 0.0f; acc[2] = 0.0f; acc[3] = 0.0f;
        RL64(FMAW)
        {
          float h64v = __builtin_bit_cast(
              float, __builtin_amdgcn_readlane(__builtin_bit_cast(int, hb), 0));
          float h65v = __builtin_bit_cast(
              float, __builtin_amdgcn_readlane(__builtin_bit_cast(int, hb), 1));
          acc[0] = fmaf(h64v, wr64, acc[0]);
          acc[1] = fmaf(h65v, wr65, acc[1]);
        }
        float pre = (acc[0] + acc[1]) + (acc[2] + acc[3]);
        sact[half][s & 1][tid] = istanh ? fast_tanh(pre) : fast_sigmoid(pre);
      }
      if (isW4 && s == 8 && scn < NSUB) {
        const int r = l >> 2, cq = l & 3;
        float* dst = &xstage[half][scn & 1][r * XSS + cq * 16];
        *(float4*)(dst + 0) = pf0; *(float4*)(dst + 4) = pf1;
        *(float4*)(dst + 8) = pf2; *(float4*)(dst + 12) = pf3;
      }
      __syncthreads();  // gates ready (the ONLY barrier per step)
      // Redundant cell update by ALL threads (full exec; readlane-safe).
      {
        const float* sa = &sact[half][s & 1][0];
        float iv = sa[l];
        float fv = sa[HH + l];
        float gv = sa[2 * HH + l];
        float ov = sa[3 * HH + l];
        float ivb = sa[jb];
        float fvb = sa[HH + jb];
        float gvb = sa[2 * HH + jb];
        float ovb = sa[3 * HH + jb];
        ca = fmaf(fv, ca, iv * gv);
        ha = ov * fast_tanh(ca);
        cb = fmaf(fvb, cb, ivb * gvb);
        hb = ovb * fast_tanh(cb);
        asm volatile("" : "+v"(ha), "+v"(hb));
      }
    }
  }
  if (tid < 64) hT[tid * BB + b] = ha;          // lane l of wave 0 holds h[l]
  else if (tid < 66) hT[tid * BB + b] = hb;     // tid 64,65 = wave1 lanes 0,1 -> h64,h65
}

// BN batch-stats folded into final linear. Single block.
__global__ __launch_bounds__(512) void bn_fc(
    const float* __restrict__ hT, const float* __restrict__ gamma,
    const float* __restrict__ beta, const float* __restrict__ fc_w,
    const float* __restrict__ fc_b, float* __restrict__ out) {
  __shared__ float w2[HH];
  __shared__ float s2[HH];
  const int tid = threadIdx.x;
  const int wv = tid >> 6;
  const int lane = tid & 63;

  for (int j = wv; j < HH; j += 8) {
    const float* p = hT + j * BB;
    float s = 0.0f, ss = 0.0f;
#pragma unroll
    for (int m = 0; m < 8; ++m) {
      float v = p[lane + (m << 6)];
      s += v;
      ss = fmaf(v, v, ss);
    }
#pragma unroll
    for (int d = 32; d >= 1; d >>= 1) {
      s += __shfl_xor(s, d);
      ss += __shfl_xor(ss, d);
    }
    if (lane == 0) {
      float mean = s * (1.0f / BB);
      float var = ss * (1.0f / BB) - mean * mean;
      float scale = gamma[j] * rsqrtf(var + 1e-5f);
      float shift = beta[j] - mean * scale;
      float fw = fc_w[j];
      w2[j] = scale * fw;
      s2[j] = shift * fw;
    }
  }
  __syncthreads();

  float acc = 0.0f;
#pragma unroll
  for (int j = 0; j < HH; ++j) acc = fmaf(hT[j * BB + tid], w2[j], acc);
  float cst = fc_b[0];
#pragma unroll
  for (int j = 0; j < HH; ++j) cst += s2[j];
  out[tid] = acc + cst;
}

extern "C" void kernel_launch(void* const* d_in, const int* in_sizes, int n_in,
                              void* d_out, int out_size, void* d_ws, size_t ws_size,
                              hipStream_t stream) {
  const float* x     = (const float*)d_in[0];
  const float* W_ih  = (const float*)d_in[1];
  const float* W_hh  = (const float*)d_in[2];
  const float* b_ih  = (const float*)d_in[3];
  const float* b_hh  = (const float*)d_in[4];
  const float* gamma = (const float*)d_in[5];
  const float* beta  = (const float*)d_in[6];
  const float* fc_w  = (const float*)d_in[7];
  const float* fc_b  = (const float*)d_in[8];
  float* out = (float*)d_out;

  unsigned short* wbhi = (unsigned short*)d_ws;                  // 34816 B
  unsigned short* wblo = (unsigned short*)((char*)d_ws + 34816); // 34816 B
  float* hT            = (float*)((char*)d_ws + 69632);          // 135168 B

  conv_w<<<68, 256, 0, stream>>>(W_ih, wbhi, wblo);
  lstm_fused<<<BB / 2, 640, 0, stream>>>(x, W_hh, b_ih, b_hh, wbhi, wblo, hT);
  bn_fc<<<1, 512, 0, stream>>>(hT, gamma, beta, fc_w, fc_b, out);
}

// Round 3
// 2547.026 us; speedup vs baseline: 1.4011x; 1.4011x over previous
//
#include <hip/hip_runtime.h>
#include <math.h>

#define BB 512   // batch
#define TT 2048  // timesteps
#define DD 64    // input dim
#define HH 66    // hidden
#define GG 264   // 4*HH gates
#define GP 272   // padded gates (17 mfma n-tiles of 16)
#define NTILE 17
#define XSS 68   // xstage row stride (floats)
#define NSUB 128 // 128 subchunks x 16 steps = 2048

typedef __attribute__((ext_vector_type(8))) __bf16 bf8_t;
typedef __attribute__((ext_vector_type(8))) unsigned short us8_t;
typedef __attribute__((ext_vector_type(4))) float f4_t;

__device__ __forceinline__ float fast_sigmoid(float x) {
  float e = __expf(-x);
  return __fdividef(1.0f, 1.0f + e);
}
__device__ __forceinline__ float fast_tanh(float x) {
  float e = __expf(2.0f * x);
  return 1.0f - __fdividef(2.0f, e + 1.0f);
}
__device__ __forceinline__ unsigned short f2bf(float f) {
  unsigned u = __builtin_bit_cast(unsigned, f);
  unsigned r = (u + 0x7fffu + ((u >> 16) & 1u)) >> 16;
  return (unsigned short)r;
}
__device__ __forceinline__ float bf2f(unsigned short h) {
  unsigned u = ((unsigned)h) << 16;
  return __builtin_bit_cast(float, u);
}
static __device__ __forceinline__ bf8_t as_bf8(us8_t u) {
  union { us8_t u; bf8_t b; } v; v.u = u; return v.b;
}
__device__ __forceinline__ void pack_hilo(float4 p0, float4 p1, us8_t& hi, us8_t& lo) {
  float v[8] = {p0.x, p0.y, p0.z, p0.w, p1.x, p1.y, p1.z, p1.w};
#pragma unroll
  for (int i = 0; i < 8; ++i) {
    unsigned short h = f2bf(v[i]);
    hi[i] = h;
    lo[i] = f2bf(v[i] - bf2f(h));
  }
}

// 66 named scalar registers for the W_hh row: SSA values, cannot be demoted
// to scratch (R1/R2: whh[66] array failed SROA -> VGPR_Count=84 -> scratch
// reloads every step were the dominant stall). Prefix wr to avoid colliding
// with local identifiers (R3 compile failure: w4).
#define RL64(X) \
  X(0) X(1) X(2) X(3) X(4) X(5) X(6) X(7) X(8) X(9) \
  X(10) X(11) X(12) X(13) X(14) X(15) X(16) X(17) X(18) X(19) \
  X(20) X(21) X(22) X(23) X(24) X(25) X(26) X(27) X(28) X(29) \
  X(30) X(31) X(32) X(33) X(34) X(35) X(36) X(37) X(38) X(39) \
  X(40) X(41) X(42) X(43) X(44) X(45) X(46) X(47) X(48) X(49) \
  X(50) X(51) X(52) X(53) X(54) X(55) X(56) X(57) X(58) X(59) \
  X(60) X(61) X(62) X(63)

#define DECLW(i) float wr##i;
#define LOADW(i) wr##i = p[(i)];

// R6: h broadcast via LDS same-address reads (HW broadcast, conflict-free),
// replacing 66x {v_readlane -> SGPR -> dependent v_fma} (VALU->SGPR->VALU
// hazard + 2x instruction count; R2 counters: 2240 cyc VALU issue/step vs
// ~830 static estimate -> the readlane pattern was the inflation).
// Each quad: one ds_read_b128 (uniform addr) + 4 VGPR-operand fmas.
#define FMAQ(q, i0, i1, i2, i3)                                           \
  {                                                                       \
    float4 hq = *(const float4*)(hb_ + (q) * 4);                          \
    a0 = fmaf(hq.x, wr##i0, a0);                                          \
    a1 = fmaf(hq.y, wr##i1, a1);                                          \
    a2 = fmaf(hq.z, wr##i2, a2);                                          \
    a3 = fmaf(hq.w, wr##i3, a3);                                          \
  }

// Kernel 0: W_ih fp32 -> bf16 hi/lo, padded to 272 rows of 64.
__global__ void conv_w(const float* __restrict__ W_ih,
                       unsigned short* __restrict__ hi,
                       unsigned short* __restrict__ lo) {
  int i = blockIdx.x * 256 + threadIdx.x;
  if (i >= GP * DD) return;
  int n = i >> 6;
  float w = (n < GG) ? W_ih[i] : 0.0f;
  unsigned short h = f2bf(w);
  hi[i] = h;
  lo[i] = f2bf(w - bf2f(h));
}

// 2 sequences per block (wave-aligned halves: tid 0..319 -> seq A,
// 320..639 -> seq B). Grid = 256 = exactly 1 block/CU (R4: occupancy 15%
// showed the 512x320 grid ran as 2 sequential rounds).
// R5: ONE barrier per step (sact exchange, parity double-buffered).
// R6: every wave redundantly computes the full cell update (lane i holds
// j=i, plus j=64+(i&1)), writes h into a WAVE-PRIVATE LDS buffer (same-wave
// DS ops are in-order -> no barrier), and the matvec reads h back as
// 16x ds_read_b128 + 1x b64 uniform-address broadcasts. No readlanes.
__global__ __launch_bounds__(640, 2) void lstm_fused(
    const float* __restrict__ x,      // [B,T,D]
    const float* __restrict__ W_hh,   // [264,66]
    const float* __restrict__ b_ih,   // [264]
    const float* __restrict__ b_hh,   // [264]
    const unsigned short* __restrict__ WbHi,  // [272,64] bf16
    const unsigned short* __restrict__ WbLo,  // [272,64] bf16
    float* __restrict__ hT)           // [66,512]
{
  __shared__ __align__(16) float tr[2][16 * GP];          // [half][tc][g]
  __shared__ __align__(16) float xstage[2][2][16 * XSS];  // [half][buf] x rows
  __shared__ __align__(16) float sact[2][2][GG];          // [half][parity][g]
  __shared__ __align__(16) float hbuf[10][68];            // per-wave h copy

  const int half = (int)(threadIdx.x >= 320);
  const int tid = threadIdx.x - 320 * half;  // 0..319 within half
  const int wid = (int)(threadIdx.x >> 6);   // 0..9 global wave id
  const int b = blockIdx.x * 2 + half;
  const int l = tid & 63;   // == threadIdx.x & 63 (half boundary is wave-aligned)
  const int w = tid >> 6;
  const bool gate = (tid < GG);
  const bool mm = (tid < 256);
  const bool isW4 = (w == 4);
  const int mlane = l & 15;
  const int quad = l >> 4;
  const int jb = 64 + (l & 1);  // second cell index per lane (h64/h65)
  float* const hb_ = &hbuf[wid][0];

  // W_hh row in 66 named scalars (clamped row for non-gate threads).
  RL64(DECLW) float wr64, wr65;
  {
    const int row = gate ? tid : (GG - 1);
    const float* p = W_hh + row * HH;
    RL64(LOADW) wr64 = p[64]; wr65 = p[65];
  }
  const bool istanh = (tid >= 2 * HH && tid < 3 * HH);

  float biasCol[5];
#pragma unroll
  for (int ti = 0; ti < 5; ++ti) {
    int tau = w + 4 * ti;
    int g = tau * 16 + mlane;
    biasCol[ti] = (mm && tau < NTILE && g < GG) ? (b_ih[g] + b_hh[g]) : 0.0f;
  }

  // Zero wave-private h buffer (wave-local; lgkmcnt orders vs first read).
  hb_[l] = 0.0f;
  if (l < 4) hb_[64 + l] = 0.0f;

  if (isW4) {
    const int r = l >> 2, cq = l & 3;
    const float* src = x + ((size_t)b * TT + r) * DD + cq * 16;
    float4 v0 = *(const float4*)(src + 0);
    float4 v1 = *(const float4*)(src + 4);
    float4 v2 = *(const float4*)(src + 8);
    float4 v3 = *(const float4*)(src + 12);
    float* dst = &xstage[half][0][r * XSS + cq * 16];
    *(float4*)(dst + 0) = v0; *(float4*)(dst + 4) = v1;
    *(float4*)(dst + 8) = v2; *(float4*)(dst + 12) = v3;
  }
  // Redundant per-wave LSTM state: lane i holds (c,h) for j=i, plus
  // (cb,hb) for j=64+(i&1).
  float ca = 0.0f, cb = 0.0f, hb_out = 0.0f, ha_out = 0.0f;
  __syncthreads();

  for (int sc = 0; sc < NSUB; ++sc) {
    // ---- x-projection (bf16 hi/lo MFMA) for the next 16 steps ----
    if (mm) {
      const float* xs = &xstage[half][sc & 1][0];
      float4 a00 = *(const float4*)&xs[mlane * XSS + quad * 8];
      float4 a01 = *(const float4*)&xs[mlane * XSS + quad * 8 + 4];
      float4 a10 = *(const float4*)&xs[mlane * XSS + 32 + quad * 8];
      float4 a11 = *(const float4*)&xs[mlane * XSS + 32 + quad * 8 + 4];
      us8_t ah0, al0, ah1, al1;
      pack_hilo(a00, a01, ah0, al0);
      pack_hilo(a10, a11, ah1, al1);
#pragma unroll
      for (int ti = 0; ti < 5; ++ti) {
        int tau = w + 4 * ti;
        if (tau < NTILE) {
          int n = tau * 16 + mlane;
          const us8_t* bh = (const us8_t*)(WbHi + n * DD + quad * 8);
          const us8_t* bl = (const us8_t*)(WbLo + n * DD + quad * 8);
          us8_t bh0 = bh[0], bh1 = bh[4];
          us8_t bl0 = bl[0], bl1 = bl[4];
          f4_t acc = {biasCol[ti], biasCol[ti], biasCol[ti], biasCol[ti]};
          acc = __builtin_amdgcn_mfma_f32_16x16x32_bf16(as_bf8(ah0), as_bf8(bh0), acc, 0, 0, 0);
          acc = __builtin_amdgcn_mfma_f32_16x16x32_bf16(as_bf8(ah1), as_bf8(bh1), acc, 0, 0, 0);
          acc = __builtin_amdgcn_mfma_f32_16x16x32_bf16(as_bf8(al0), as_bf8(bh0), acc, 0, 0, 0);
          acc = __builtin_amdgcn_mfma_f32_16x16x32_bf16(as_bf8(al1), as_bf8(bh1), acc, 0, 0, 0);
          acc = __builtin_amdgcn_mfma_f32_16x16x32_bf16(as_bf8(ah0), as_bf8(bl0), acc, 0, 0, 0);
          acc = __builtin_amdgcn_mfma_f32_16x16x32_bf16(as_bf8(ah1), as_bf8(bl1), acc, 0, 0, 0);
          int g = tau * 16 + mlane;
#pragma unroll
          for (int r = 0; r < 4; ++r) tr[half][(quad * 4 + r) * GP + g] = acc[r];
        }
      }
    }
    __syncthreads();  // tr ready

    const int scn = sc + 1;
    float4 pf0, pf1, pf2, pf3;
    if (isW4 && scn < NSUB) {
      const int r = l >> 2, cq = l & 3;
      const float* src = x + ((size_t)b * TT + scn * 16 + r) * DD + cq * 16;
      pf0 = *(const float4*)(src + 0);
      pf1 = *(const float4*)(src + 4);
      pf2 = *(const float4*)(src + 8);
      pf3 = *(const float4*)(src + 12);
    }

    for (int s = 0; s < 16; ++s) {
      if (gate) {
        float a0 = tr[half][s * GP + tid];  // x_proj + bias
        float a1 = 0.0f, a2 = 0.0f, a3 = 0.0f;
        FMAQ(0, 0, 1, 2, 3)   FMAQ(1, 4, 5, 6, 7)
        FMAQ(2, 8, 9, 10, 11) FMAQ(3, 12, 13, 14, 15)
        FMAQ(4, 16, 17, 18, 19) FMAQ(5, 20, 21, 22, 23)
        FMAQ(6, 24, 25, 26, 27) FMAQ(7, 28, 29, 30, 31)
        FMAQ(8, 32, 33, 34, 35) FMAQ(9, 36, 37, 38, 39)
        FMAQ(10, 40, 41, 42, 43) FMAQ(11, 44, 45, 46, 47)
        FMAQ(12, 48, 49, 50, 51) FMAQ(13, 52, 53, 54, 55)
        FMAQ(14, 56, 57, 58, 59) FMAQ(15, 60, 61, 62, 63)
        {
          float2 h64v = *(const float2*)(hb_ + 64);
          a0 = fmaf(h64v.x, wr64, a0);
          a1 = fmaf(h64v.y, wr65, a1);
        }
        float pre = (a0 + a1) + (a2 + a3);
        sact[half][s & 1][tid] = istanh ? fast_tanh(pre) : fast_sigmoid(pre);
      }
      if (isW4 && s == 8 && scn < NSUB) {
        const int r = l >> 2, cq = l & 3;
        float* dst = &xstage[half][scn & 1][r * XSS + cq * 16];
        *(float4*)(dst + 0) = pf0; *(float4*)(dst + 4) = pf1;
        *(float4*)(dst + 8) = pf2; *(float4*)(dst + 12) = pf3;
      }
      __syncthreads();  // gates ready (the ONLY barrier per step)
      // Redundant cell update by ALL threads at full exec; each wave then
      // refreshes its private h copy. Same-wave DS ordering makes the
      // write->read (next step's FMAQ) dependency barrier-free.
      {
        const float* sa = &sact[half][s & 1][0];
        float iv = sa[l];
        float fv = sa[HH + l];
        float gv = sa[2 * HH + l];
        float ov = sa[3 * HH + l];
        float ivb = sa[jb];
        float fvb = sa[HH + jb];
        float gvb = sa[2 * HH + jb];
        float ovb = sa[3 * HH + jb];
        ca = fmaf(fv, ca, iv * gv);
        ha_out = ov * fast_tanh(ca);
        cb = fmaf(fvb, cb, ivb * gvb);
        hb_out = ovb * fast_tanh(cb);
        hb_[l] = ha_out;
        if (l < 2) hb_[64 + l] = hb_out;
      }
    }
  }
  if (tid < 64) hT[tid * BB + b] = ha_out;       // wave 0 lane l holds h[l]
  else if (tid < 66) hT[tid * BB + b] = hb_out;  // tid 64,65 -> h64,h65
}

// BN batch-stats folded into final linear. Single block.
__global__ __launch_bounds__(512) void bn_fc(
    const float* __restrict__ hT, const float* __restrict__ gamma,
    const float* __restrict__ beta, const float* __restrict__ fc_w,
    const float* __restrict__ fc_b, float* __restrict__ out) {
  __shared__ float w2[HH];
  __shared__ float s2[HH];
  const int tid = threadIdx.x;
  const int wv = tid >> 6;
  const int lane = tid & 63;

  for (int j = wv; j < HH; j += 8) {
    const float* p = hT + j * BB;
    float s = 0.0f, ss = 0.0f;
#pragma unroll
    for (int m = 0; m < 8; ++m) {
      float v = p[lane + (m << 6)];
      s += v;
      ss = fmaf(v, v, ss);
    }
#pragma unroll
    for (int d = 32; d >= 1; d >>= 1) {
      s += __shfl_xor(s, d);
      ss += __shfl_xor(ss, d);
    }
    if (lane == 0) {
      float mean = s * (1.0f / BB);
      float var = ss * (1.0f / BB) - mean * mean;
      float scale = gamma[j] * rsqrtf(var + 1e-5f);
      float shift = beta[j] - mean * scale;
      float fw = fc_w[j];
      w2[j] = scale * fw;
      s2[j] = shift * fw;
    }
  }
  __syncthreads();

  float acc = 0.0f;
#pragma unroll
  for (int j = 0; j < HH; ++j) acc = fmaf(hT[j * BB + tid], w2[j], acc);
  float cst = fc_b[0];
#pragma unroll
  for (int j = 0; j < HH; ++j) cst += s2[j];
  out[tid] = acc + cst;
}

extern "C" void kernel_launch(void* const* d_in, const int* in_sizes, int n_in,
                              void* d_out, int out_size, void* d_ws, size_t ws_size,
                              hipStream_t stream) {
  const float* x     = (const float*)d_in[0];
  const float* W_ih  = (const float*)d_in[1];
  const float* W_hh  = (const float*)d_in[2];
  const float* b_ih  = (const float*)d_in[3];
  const float* b_hh  = (const float*)d_in[4];
  const float* gamma = (const float*)d_in[5];
  const float* beta  = (const float*)d_in[6];
  const float* fc_w  = (const float*)d_in[7];
  const float* fc_b  = (const float*)d_in[8];
  float* out = (float*)d_out;

  unsigned short* wbhi = (unsigned short*)d_ws;                  // 34816 B
  unsigned short* wblo = (unsigned short*)((char*)d_ws + 34816); // 34816 B
  float* hT            = (float*)((char*)d_ws + 69632);          // 135168 B

  conv_w<<<68, 256, 0, stream>>>(W_ih, wbhi, wblo);
  lstm_fused<<<BB / 2, 640, 0, stream>>>(x, W_hh, b_ih, b_hh, wbhi, wblo, hT);
  bn_fc<<<1, 512, 0, stream>>>(hT, gamma, beta, fc_w, fc_b, out);
}